// Round 8
// baseline (66.769 us; speedup 1.0000x reference)
//
#include <hip/hip_runtime.h>

#define S_LEN 2048
#define B_DIM 32
#define H_DIM 1024
#define KSPLIT 4     // k-split partials in proj
#define KCH (H_DIM / KSPLIT)  // 256
#define SPB 8        // consecutive s-slabs per energy block (1 MB contiguous)

typedef float fx4 __attribute__((ext_vector_type(4)));

// ---------------------------------------------------------------------------
// Kernel 1: vp[kp,b,h] = sum_{k in chunk kp} dec[b,k] * W[k,h]
// Grid: (1, B, KSPLIT) = 128 blocks x 256 threads. Thread t owns h = 4t
// via fx4. W is HBM-cold every replay (enc stream evicts L3); 128 blocks
// with 256 fx4 loads each give ample bytes in flight. dec -> s_load.
// ---------------------------------------------------------------------------
__global__ __launch_bounds__(256) void proj_kernel(
    const float* __restrict__ dec, const float* __restrict__ W,
    float* __restrict__ vp)
{
    const int t  = threadIdx.x;
    const int b  = blockIdx.y;
    const int kp = blockIdx.z;
    const int k0 = kp * KCH;
    const float* __restrict__ drow = dec + (size_t)b * H_DIM;

    fx4 acc = {0.f, 0.f, 0.f, 0.f};
#pragma unroll 8
    for (int kk = 0; kk < KCH; ++kk) {
        const int k = k0 + kk;
        const fx4 w = reinterpret_cast<const fx4*>(W + (size_t)k * H_DIM)[t];
        acc += drow[k] * w;              // uniform scalar -> s_load
    }
    reinterpret_cast<fx4*>(vp + ((size_t)kp * B_DIM + b) * H_DIM)[t] = acc;
}

// ---------------------------------------------------------------------------
// Kernel 2: e[b,s] = dot(enc[s,b,:], v[b,:]),  v = sum of KSPLIT partials.
// TRANSPOSED STREAMING: 256 blocks x 512 threads (8 waves), 1 block/CU.
// Block p (XCD-swizzled: logical = (p%8)*32 + p/8, so each XCD owns a
// CONTIGUOUS 32 MB range) covers s in [logical*8, logical*8+8): 1 MB of enc
// read fully sequentially. Wave wv owns b-quad {4wv..4wv+3}; per s-step it
// reads one contiguous 16 KB chunk as 16 float4 loads (load i: local
// b = i/4, h4 = (i%4)*64+lane). vf (16 fx4) loaded once from L2, reused
// for all 8 s-steps. A/B double-buffer pipelines s-step t+1's loads under
// s-step t's dot+reduce. ~215 VGPR, 2 waves/SIMD.
// ---------------------------------------------------------------------------
__global__ __launch_bounds__(512, 2) void energy_kernel(
    const float* __restrict__ enc, const float* __restrict__ vp,
    float* __restrict__ e)
{
    const int lane = threadIdx.x & 63;
    const int wv   = threadIdx.x >> 6;              // 0..7
    const int p    = blockIdx.x;                    // 0..255
    const int logical = (p & 7) * 32 + (p >> 3);    // XCD-contiguous
    const int s0   = logical * SPB;
    const int b0   = wv * 4;                        // wave's b-quad

    // vf[j][q] = v[b0+j][(q*64+lane) fx4], summed over KSPLIT partials (L2)
    fx4 vf[4][4];
#pragma unroll
    for (int j = 0; j < 4; ++j) {
#pragma unroll
        for (int q = 0; q < 4; ++q) {
            fx4 t = {0.f, 0.f, 0.f, 0.f};
#pragma unroll
            for (int kp = 0; kp < KSPLIT; ++kp) {
                const fx4* __restrict__ pr = reinterpret_cast<const fx4*>(
                    vp + ((size_t)kp * B_DIM + b0 + j) * H_DIM);
                t += pr[q * 64 + lane];
            }
            vf[j][q] = t;
        }
    }

    auto LOAD = [&](fx4 (&A)[16], int s) {
        const fx4* __restrict__ ep = reinterpret_cast<const fx4*>(
            enc + ((size_t)s * B_DIM + b0) * H_DIM);
#pragma unroll
        for (int i = 0; i < 16; ++i) A[i] = ep[i * 64 + lane];
    };
    auto DOT = [&](fx4 (&A)[16], int s) {
        float acc[4] = {0.f, 0.f, 0.f, 0.f};
#pragma unroll
        for (int i = 0; i < 16; ++i) {
            const fx4 a = A[i];
            const fx4 w = vf[i >> 2][i & 3];
            acc[i >> 2] += a.x * w.x + a.y * w.y + a.z * w.z + a.w * w.w;
        }
#pragma unroll
        for (int off = 32; off; off >>= 1) {
#pragma unroll
            for (int j = 0; j < 4; ++j)
                acc[j] += __shfl_xor(acc[j], off, 64);
        }
        if (lane == 0) {
#pragma unroll
            for (int j = 0; j < 4; ++j)
                e[(size_t)(b0 + j) * S_LEN + s] = acc[j];
        }
    };

    fx4 A[16], Bb[16];
    LOAD(A, s0);
#pragma unroll
    for (int t = 0; t < SPB; t += 2) {
        LOAD(Bb, s0 + t + 1);
        DOT(A, s0 + t);
        if (t + 2 < SPB) LOAD(A, s0 + t + 2);
        DOT(Bb, s0 + t + 1);
    }
}

// ---------------------------------------------------------------------------
// Kernel 3: out[b,0,s] = softmax_s(e[b,s]).  One block per b (32 blocks).
// Bias term c[b] omitted: constant per row, softmax-invariant.
// ---------------------------------------------------------------------------
__global__ __launch_bounds__(256) void softmax_kernel(
    const float* __restrict__ e, float* __restrict__ out)
{
    __shared__ float red[4];
    const int b    = blockIdx.x;
    const int tid  = threadIdx.x;
    const int lane = tid & 63;
    const int wv   = tid >> 6;
    const float* __restrict__ row = e + (size_t)b * S_LEN;

    float vals[8];
    float m = -1e30f;
#pragma unroll
    for (int i = 0; i < 8; ++i) {
        vals[i] = row[tid + 256 * i];
        m = fmaxf(m, vals[i]);
    }
#pragma unroll
    for (int off = 32; off; off >>= 1)
        m = fmaxf(m, __shfl_xor(m, off, 64));
    if (lane == 0) red[wv] = m;
    __syncthreads();
    m = fmaxf(fmaxf(red[0], red[1]), fmaxf(red[2], red[3]));

    float sum = 0.0f;
#pragma unroll
    for (int i = 0; i < 8; ++i) {
        vals[i] = __expf(vals[i] - m);
        sum += vals[i];
    }
#pragma unroll
    for (int off = 32; off; off >>= 1)
        sum += __shfl_xor(sum, off, 64);
    __syncthreads();                 // red reuse hazard
    if (lane == 0) red[wv] = sum;
    __syncthreads();
    sum = red[0] + red[1] + red[2] + red[3];

    const float inv = 1.0f / sum;
#pragma unroll
    for (int i = 0; i < 8; ++i)
        out[(size_t)b * S_LEN + tid + 256 * i] = vals[i] * inv;
}

// ---------------------------------------------------------------------------
extern "C" void kernel_launch(void* const* d_in, const int* in_sizes, int n_in,
                              void* d_out, int out_size, void* d_ws, size_t ws_size,
                              hipStream_t stream)
{
    const float* dec = (const float*)d_in[0];   // [B,H]
    const float* enc = (const float*)d_in[1];   // [S,B,H]
    const float* W   = (const float*)d_in[2];   // [H,H]
    // d_in[3] = bias: constant-per-row contribution, softmax-invariant -> unused
    float* out = (float*)d_out;                 // [B,1,S] flat

    float* vp = (float*)d_ws;                   // KSPLIT*B*H floats (512 KiB)
    float* e  = vp + KSPLIT * B_DIM * H_DIM;    // B*S floats (256 KiB)

    proj_kernel<<<dim3(1, B_DIM, KSPLIT), 256, 0, stream>>>(dec, W, vp);
    energy_kernel<<<dim3(256), 512, 0, stream>>>(enc, vp, e);
    softmax_kernel<<<B_DIM, 256, 0, stream>>>(e, out);
}

// Round 9
// 64.081 us; speedup vs baseline: 1.0420x; 1.0420x over previous
//
#include <hip/hip_runtime.h>

#define S_LEN 2048
#define B_DIM 32
#define H_DIM 1024
#define ROWS 8       // s-rows per wave in energy kernel (round-4 optimum)
#define KSPLIT 4     // k-split partials in proj (round-4 optimum)
#define KCH (H_DIM / KSPLIT)  // 256

typedef float fx4 __attribute__((ext_vector_type(4)));

// ---------------------------------------------------------------------------
// Kernel 1: vp[kp,b,h] = sum_{k in chunk kp} dec[b,k] * W[k,h]
// EXACT round-4 proj: grid (H/256, B, KSPLIT) = (4, 32, 4) = 512 blocks x
// 256 threads. W is HBM-cold every replay (enc stream evicts L3); 512
// blocks give 2/CU for latency hiding. dec loads thread-uniform -> s_load;
// W loads coalesced. No atomics, no memset: energy sums the partials.
// ---------------------------------------------------------------------------
__global__ __launch_bounds__(256) void proj_kernel(
    const float* __restrict__ dec, const float* __restrict__ W,
    float* __restrict__ vp)
{
    const int h  = blockIdx.x * 256 + threadIdx.x;
    const int b  = blockIdx.y;
    const int kp = blockIdx.z;
    const int k0 = kp * KCH;
    const float* __restrict__ drow = dec + (size_t)b * H_DIM;

    float a0 = 0.f, a1 = 0.f, a2 = 0.f, a3 = 0.f;
    for (int kk = 0; kk < KCH; kk += 4) {
        const int k = k0 + kk;
        a0 += drow[k + 0] * W[(size_t)(k + 0) * H_DIM + h];
        a1 += drow[k + 1] * W[(size_t)(k + 1) * H_DIM + h];
        a2 += drow[k + 2] * W[(size_t)(k + 2) * H_DIM + h];
        a3 += drow[k + 3] * W[(size_t)(k + 3) * H_DIM + h];
    }
    vp[((size_t)kp * B_DIM + b) * H_DIM + h] = (a0 + a1) + (a2 + a3);
}

// ---------------------------------------------------------------------------
// Kernel 2: e[b,s] = dot(enc[s,b,:], v[b,:]),  v = sum of 4 partials.
// EXACT round-4 structure; ONE change: enc loads are NONTEMPORAL.
// enc is 256 MiB (== L3 size), each line used exactly once -> nt skips
// L2/L3 allocation churn and leaves vp resident. Grid (B/4, S/ROWS) =
// (8, 256), x fastest; wave wv owns b = 4x+wv and 8 consecutive s.
// ---------------------------------------------------------------------------
__global__ __launch_bounds__(256) void energy_kernel(
    const float* __restrict__ enc, const float* __restrict__ vp,
    float* __restrict__ e)
{
    const int lane = threadIdx.x & 63;
    const int wv   = threadIdx.x >> 6;
    const int b    = blockIdx.x * 4 + wv;
    const int s0   = blockIdx.y * ROWS;

    fx4 vf[4];
#pragma unroll
    for (int i = 0; i < 4; ++i) {
        fx4 t = {0.f, 0.f, 0.f, 0.f};
#pragma unroll
        for (int kp = 0; kp < KSPLIT; ++kp) {
            const fx4* __restrict__ p = reinterpret_cast<const fx4*>(
                vp + ((size_t)kp * B_DIM + b) * H_DIM);
            t += p[lane + 64 * i];
        }
        vf[i] = t;
    }

    float acc[ROWS];
    for (int g = 0; g < 2; ++g) {
        fx4 a[4][4];
#pragma unroll
        for (int r = 0; r < 4; ++r) {
            const fx4* __restrict__ ep = reinterpret_cast<const fx4*>(
                enc + ((size_t)(s0 + g * 4 + r) * B_DIM + b) * H_DIM);
#pragma unroll
            for (int i = 0; i < 4; ++i)
                a[r][i] = __builtin_nontemporal_load(&ep[lane + 64 * i]);
        }
#pragma unroll
        for (int r = 0; r < 4; ++r) {
            float t = 0.f;
#pragma unroll
            for (int i = 0; i < 4; ++i)
                t += a[r][i].x * vf[i].x + a[r][i].y * vf[i].y +
                     a[r][i].z * vf[i].z + a[r][i].w * vf[i].w;
            acc[g * 4 + r] = t;
        }
    }

#pragma unroll
    for (int off = 32; off; off >>= 1) {
#pragma unroll
        for (int r = 0; r < ROWS; ++r)
            acc[r] += __shfl_xor(acc[r], off, 64);
    }

    if (lane == 0) {
        fx4 o0, o1;
        o0.x = acc[0]; o0.y = acc[1]; o0.z = acc[2]; o0.w = acc[3];
        o1.x = acc[4]; o1.y = acc[5]; o1.z = acc[6]; o1.w = acc[7];
        fx4* ep = reinterpret_cast<fx4*>(e + (size_t)b * S_LEN + s0);
        ep[0] = o0;
        ep[1] = o1;
    }
}

// ---------------------------------------------------------------------------
// Kernel 3: out[b,0,s] = softmax_s(e[b,s]).  One block per b (32 blocks).
// Bias term c[b] omitted: constant per row, softmax-invariant.
// ---------------------------------------------------------------------------
__global__ __launch_bounds__(256) void softmax_kernel(
    const float* __restrict__ e, float* __restrict__ out)
{
    __shared__ float red[4];
    const int b    = blockIdx.x;
    const int tid  = threadIdx.x;
    const int lane = tid & 63;
    const int wv   = tid >> 6;
    const float* __restrict__ row = e + (size_t)b * S_LEN;

    float vals[8];
    float m = -1e30f;
#pragma unroll
    for (int i = 0; i < 8; ++i) {
        vals[i] = row[tid + 256 * i];
        m = fmaxf(m, vals[i]);
    }
#pragma unroll
    for (int off = 32; off; off >>= 1)
        m = fmaxf(m, __shfl_xor(m, off, 64));
    if (lane == 0) red[wv] = m;
    __syncthreads();
    m = fmaxf(fmaxf(red[0], red[1]), fmaxf(red[2], red[3]));

    float sum = 0.0f;
#pragma unroll
    for (int i = 0; i < 8; ++i) {
        vals[i] = __expf(vals[i] - m);
        sum += vals[i];
    }
#pragma unroll
    for (int off = 32; off; off >>= 1)
        sum += __shfl_xor(sum, off, 64);
    __syncthreads();                 // red reuse hazard
    if (lane == 0) red[wv] = sum;
    __syncthreads();
    sum = red[0] + red[1] + red[2] + red[3];

    const float inv = 1.0f / sum;
#pragma unroll
    for (int i = 0; i < 8; ++i)
        out[(size_t)b * S_LEN + tid + 256 * i] = vals[i] * inv;
}

// ---------------------------------------------------------------------------
extern "C" void kernel_launch(void* const* d_in, const int* in_sizes, int n_in,
                              void* d_out, int out_size, void* d_ws, size_t ws_size,
                              hipStream_t stream)
{
    const float* dec = (const float*)d_in[0];   // [B,H]
    const float* enc = (const float*)d_in[1];   // [S,B,H]
    const float* W   = (const float*)d_in[2];   // [H,H]
    // d_in[3] = bias: constant-per-row contribution, softmax-invariant -> unused
    float* out = (float*)d_out;                 // [B,1,S] flat

    float* vp = (float*)d_ws;                   // KSPLIT*B*H floats (512 KiB)
    float* e  = vp + KSPLIT * B_DIM * H_DIM;    // B*S floats (256 KiB)

    proj_kernel<<<dim3(H_DIM / 256, B_DIM, KSPLIT), 256, 0, stream>>>(dec, W, vp);
    energy_kernel<<<dim3(B_DIM / 4, S_LEN / ROWS), 256, 0, stream>>>(enc, vp, e);
    softmax_kernel<<<B_DIM, 256, 0, stream>>>(e, out);
}